// Round 5
// baseline (552.903 us; speedup 1.0000x reference)
//
#include <hip/hip_runtime.h>

#define HEADS 4
#define OUTF 64
#define INF 64
#define NT 32  // nodes per proj block

// --- detect whether edge_index arrived as int64 (odd dwords all zero) or int32 ---
__global__ __launch_bounds__(64) void detect_i64(const int* __restrict__ ei, int* __restrict__ flag) {
    if (threadIdx.x == 0) {
        int all0 = 1;
        #pragma unroll
        for (int i = 1; i < 64; i += 2) all0 &= (ei[i] == 0);
        *flag = all0;  // 1 -> int64 layout, 0 -> int32 layout
    }
}

// --- fused: dst-degree histogram + LDS-tiled GEMM h = x@W (bf16 out) + s_src/s_dst ---
// Block: 256 threads, 32 nodes. W staged in LDS in two 32-row halves (32KB f32),
// x tile 8KB f32. Thread tile: 8 nodes x 4 feats, acc in registers.
__global__ __launch_bounds__(256, 4) void proj_kernel(
    const float* __restrict__ x, const float* __restrict__ W,
    const float* __restrict__ a_src, const float* __restrict__ a_dst,
    ushort* __restrict__ h_bf, float* __restrict__ ssrc, float* __restrict__ sdst,
    const int* __restrict__ ei, const int* __restrict__ flag,
    int* __restrict__ cnt, int nNodes, int E)
{
    __shared__ float W_lds[32 * 256];  // 32KB: rows f (within half), cols head*64+o
    __shared__ float x_lds[NT * 64];   // 8KB: [node][f], same layout as global

    const int t = threadIdx.x;

    // fused histogram: this block's slice of edges
    const int estride = gridDim.x * 256;
    const int i64 = *flag;
    for (int i = blockIdx.x * 256 + t; i < E; i += estride) {
        const int dst = i64 ? ei[2 * ((size_t)E + i)] : ei[(size_t)E + i];
        atomicAdd(&cnt[dst], 1);
    }

    // stage x tile (clamped at tail)
    const int n0 = blockIdx.x * NT;
    #pragma unroll
    for (int k = 0; k < 2; ++k) {
        const int e4 = (k * 256 + t) * 4;               // dword idx in tile, mult of 4
        const int n  = e4 >> 6;
        const int gn = min(n0 + n, nNodes - 1);
        const float4 v = *reinterpret_cast<const float4*>(x + (size_t)gn * 64 + (e4 & 63));
        *reinterpret_cast<float4*>(&x_lds[e4]) = v;
    }

    const int g   = t & 63;      // feat group 0..63
    const int o4  = g * 4;       // global out-feat = head*64 + o, 4 consecutive
    const int ht  = g >> 4;      // head of this feat group
    const int ny  = (t >> 6) * 8;  // first node (within tile) of this wave

    float acc[8][4] = {{0.f}};

    #pragma unroll
    for (int p = 0; p < 2; ++p) {
        // stage W rows [32p, 32p+32): W[h][f][o] -> W_lds[fr*256 + h*64 + o]
        #pragma unroll
        for (int k = 0; k < 8; ++k) {
            const int e4 = (k * 256 + t) * 4;           // 0..8191, mult of 4
            const int h  = e4 >> 11;
            const int fr = (e4 >> 6) & 31;
            const int o  = e4 & 63;
            const float4 v = *reinterpret_cast<const float4*>(
                W + (size_t)h * 4096 + (size_t)(32 * p + fr) * 64 + o);
            *reinterpret_cast<float4*>(&W_lds[fr * 256 + h * 64 + o]) = v;
        }
        __syncthreads();

        for (int fr = 0; fr < 32; fr += 4) {
            float4 xv[8];
            #pragma unroll
            for (int j = 0; j < 8; ++j)
                xv[j] = *reinterpret_cast<const float4*>(&x_lds[(ny + j) * 64 + 32 * p + fr]);
            #pragma unroll
            for (int ff = 0; ff < 4; ++ff) {
                const float4 wv = *reinterpret_cast<const float4*>(&W_lds[(fr + ff) * 256 + o4]);
                #pragma unroll
                for (int j = 0; j < 8; ++j) {
                    const float xs = (ff == 0) ? xv[j].x : (ff == 1) ? xv[j].y
                                   : (ff == 2) ? xv[j].z : xv[j].w;
                    acc[j][0] = fmaf(xs, wv.x, acc[j][0]);
                    acc[j][1] = fmaf(xs, wv.y, acc[j][1]);
                    acc[j][2] = fmaf(xs, wv.z, acc[j][2]);
                    acc[j][3] = fmaf(xs, wv.w, acc[j][3]);
                }
            }
        }
        __syncthreads();  // before overwriting W_lds with next half
    }

    // epilogue: bf16 h + attention dot products
    const float4 as4 = *reinterpret_cast<const float4*>(&a_src[o4]);
    const float4 ad4 = *reinterpret_cast<const float4*>(&a_dst[o4]);
    #pragma unroll
    for (int j = 0; j < 8; ++j) {
        const int n = n0 + ny + j;
        float rs = acc[j][0] * as4.x + acc[j][1] * as4.y + acc[j][2] * as4.z + acc[j][3] * as4.w;
        float rd = acc[j][0] * ad4.x + acc[j][1] * ad4.y + acc[j][2] * ad4.z + acc[j][3] * ad4.w;
        #pragma unroll
        for (int off = 1; off < 16; off <<= 1) {   // reduce the 16 lanes of this head
            rs += __shfl_xor(rs, off);
            rd += __shfl_xor(rd, off);
        }
        if (n < nNodes) {
            unsigned r0 = __float_as_uint(acc[j][0]); r0 = (r0 + 0x7fffu + ((r0 >> 16) & 1u)) >> 16;
            unsigned r1 = __float_as_uint(acc[j][1]); r1 = (r1 + 0x7fffu + ((r1 >> 16) & 1u)) >> 16;
            unsigned r2 = __float_as_uint(acc[j][2]); r2 = (r2 + 0x7fffu + ((r2 >> 16) & 1u)) >> 16;
            unsigned r3 = __float_as_uint(acc[j][3]); r3 = (r3 + 0x7fffu + ((r3 >> 16) & 1u)) >> 16;
            uint2 hb;
            hb.x = r0 | (r1 << 16);
            hb.y = r2 | (r3 << 16);
            *reinterpret_cast<uint2*>(&h_bf[(size_t)n * 256 + o4]) = hb;
            if ((t & 15) == 0) { ssrc[n * 4 + ht] = rs; sdst[n * 4 + ht] = rd; }
        }
    }
}

// --- parallel scan, stage 1: per-block (2048 elems) partial sums ---
__global__ __launch_bounds__(256) void scan_partial(
    const int* __restrict__ cnt, int* __restrict__ bsum, int N)
{
    const int t = threadIdx.x, lane = t & 63, wv = t >> 6;
    const int i0 = blockIdx.x * 2048 + t * 8;
    int s = 0;
    #pragma unroll
    for (int k = 0; k < 8; ++k) if (i0 + k < N) s += cnt[i0 + k];
    #pragma unroll
    for (int off = 32; off > 0; off >>= 1) s += __shfl_xor(s, off);
    __shared__ int ws[4];
    if (lane == 0) ws[wv] = s;
    __syncthreads();
    if (t == 0) bsum[blockIdx.x] = ws[0] + ws[1] + ws[2] + ws[3];
}

// --- stage 2: exclusive scan of block sums (nb <= 64, trivial serial) ---
__global__ __launch_bounds__(64) void scan_bsum(int* __restrict__ bsum, int nb)
{
    if (threadIdx.x == 0) {
        int run = 0;
        for (int b = 0; b < nb; ++b) { int v = bsum[b]; bsum[b] = run; run += v; }
    }
}

// --- stage 3: per-block re-scan with offset -> row_start[0..N], cursor[0..N) ---
__global__ __launch_bounds__(256) void scan_final(
    const int* __restrict__ cnt, const int* __restrict__ bsum,
    int* __restrict__ row_start, int* __restrict__ cursor, int N)
{
    const int t = threadIdx.x, lane = t & 63, wv = t >> 6;
    const int i0 = blockIdx.x * 2048 + t * 8;
    int v[8], s = 0;
    #pragma unroll
    for (int k = 0; k < 8; ++k) { v[k] = (i0 + k < N) ? cnt[i0 + k] : 0; s += v[k]; }
    int incl = s;
    #pragma unroll
    for (int d = 1; d < 64; d <<= 1) {
        int tm = __shfl_up(incl, d);
        if (lane >= d) incl += tm;
    }
    __shared__ int ws[4];
    if (lane == 63) ws[wv] = incl;
    __syncthreads();
    int woff = 0;
    for (int k = 0; k < wv; ++k) woff += ws[k];
    int run = bsum[blockIdx.x] + woff + incl - s;  // exclusive prefix at i0
    #pragma unroll
    for (int k = 0; k < 8; ++k) {
        if (i0 + k < N) { cursor[i0 + k] = run; row_start[i0 + k + 1] = run + v[k]; }
        run += v[k];
    }
    if (blockIdx.x == 0 && t == 0) row_start[0] = 0;
}

// --- place each edge's src into its dst's CSR slot ---
__global__ __launch_bounds__(256) void fill_kernel(
    const int* __restrict__ ei, const int* __restrict__ flag,
    int* __restrict__ cursor, int* __restrict__ csr_src, int E)
{
    const int i = blockIdx.x * 256 + threadIdx.x;
    if (i >= E) return;
    int src, dst;
    if (*flag) { src = ei[2 * (size_t)i]; dst = ei[2 * ((size_t)E + i)]; }
    else       { src = ei[i];             dst = ei[(size_t)E + i]; }
    const int pos = atomicAdd(&cursor[dst], 1);
    csr_src[pos] = src;
}

// --- one WAVE per dst node; lane covers 4 output features (uint2 bf16x4 loads) ---
__global__ __launch_bounds__(256) void gather_kernel(
    const int* __restrict__ row_start, const int* __restrict__ csr_src,
    const ushort* __restrict__ h_bf, const float* __restrict__ ssrc,
    const float* __restrict__ sdst, float* __restrict__ out, int N)
{
    const int tid  = threadIdx.x;
    const int lane = tid & 63;
    const int n    = blockIdx.x * 4 + (tid >> 6);
    if (n >= N) return;
    const int head = lane >> 4;  // features lane*4..lane*4+3 all in this head
    const int start = row_start[n];
    const int end   = row_start[n + 1];
    const float sd  = sdst[n * 4 + head];

    float a0 = 0.f, a1 = 0.f, a2 = 0.f, a3 = 0.f, wsum = 0.f;
    int c = start;
    for (; c + 64 <= end; c += 64) {
        const int sv = csr_src[c + lane];
        #pragma unroll 4
        for (int j = 0; j < 64; ++j) {
            const int s = __shfl(sv, j);
            float e = ssrc[s * 4 + head] + sd;
            e = e >= 0.f ? e : 0.2f * e;
            const float w = __expf(e);
            const uint2 hv = *reinterpret_cast<const uint2*>(h_bf + ((size_t)s << 8) + (lane << 2));
            a0 = fmaf(w, __uint_as_float(hv.x << 16), a0);
            a1 = fmaf(w, __uint_as_float(hv.x & 0xffff0000u), a1);
            a2 = fmaf(w, __uint_as_float(hv.y << 16), a2);
            a3 = fmaf(w, __uint_as_float(hv.y & 0xffff0000u), a3);
            wsum += w;
        }
    }
    const int rem = end - c;
    if (rem > 0) {
        const int sv = (lane < rem) ? csr_src[c + lane] : 0;
        for (int j = 0; j < rem; ++j) {
            const int s = __shfl(sv, j);
            float e = ssrc[s * 4 + head] + sd;
            e = e >= 0.f ? e : 0.2f * e;
            const float w = __expf(e);
            const uint2 hv = *reinterpret_cast<const uint2*>(h_bf + ((size_t)s << 8) + (lane << 2));
            a0 = fmaf(w, __uint_as_float(hv.x << 16), a0);
            a1 = fmaf(w, __uint_as_float(hv.x & 0xffff0000u), a1);
            a2 = fmaf(w, __uint_as_float(hv.y << 16), a2);
            a3 = fmaf(w, __uint_as_float(hv.y & 0xffff0000u), a3);
            wsum += w;
        }
    }
    const float inv = 1.f / (wsum + 1e-16f);
    float4 o;
    o.x = a0 * inv; o.y = a1 * inv; o.z = a2 * inv; o.w = a3 * inv;
    *reinterpret_cast<float4*>(out + ((size_t)n << 8) + (lane << 2)) = o;
}

extern "C" void kernel_launch(void* const* d_in, const int* in_sizes, int n_in,
                              void* d_out, int out_size, void* d_ws, size_t ws_size,
                              hipStream_t stream) {
    const float* x     = (const float*)d_in[0];
    const int*   ei    = (const int*)d_in[1];
    const float* W     = (const float*)d_in[2];
    const float* a_src = (const float*)d_in[3];
    const float* a_dst = (const float*)d_in[4];
    float*       out   = (float*)d_out;

    const int N = in_sizes[0] / INF;   // 50000
    const int E = in_sizes[1] / 2;     // 800000

    // workspace: h_bf[N*256 ushort] | ssrc[N*4] | sdst[N*4] | cnt[N] | row_start[N+1] | cursor[N] | csr_src[E] | bsum[64] | flag
    ushort* h_bf     = (ushort*)d_ws;
    float* ssrc      = (float*)(h_bf + (size_t)N * 256);
    float* sdst      = ssrc + (size_t)N * 4;
    int*   cnt       = (int*)(sdst + (size_t)N * 4);
    int*   row_start = cnt + N;
    int*   cursor    = row_start + (N + 1);
    int*   csr_src   = cursor + N;
    int*   bsum      = csr_src + E;
    int*   flag      = bsum + 64;

    const int nb = (N + 2047) / 2048;

    hipMemsetAsync(cnt, 0, (size_t)N * sizeof(int), stream);

    detect_i64<<<1, 64, 0, stream>>>(ei, flag);
    proj_kernel<<<(N + NT - 1) / NT, 256, 0, stream>>>(x, W, a_src, a_dst, h_bf, ssrc, sdst, ei, flag, cnt, N, E);
    scan_partial<<<nb, 256, 0, stream>>>(cnt, bsum, N);
    scan_bsum<<<1, 64, 0, stream>>>(bsum, nb);
    scan_final<<<nb, 256, 0, stream>>>(cnt, bsum, row_start, cursor, N);
    fill_kernel<<<(E + 255) / 256, 256, 0, stream>>>(ei, flag, cursor, csr_src, E);
    gather_kernel<<<(N + 3) / 4, 256, 0, stream>>>(row_start, csr_src, h_bf, ssrc, sdst, out, N);
}

// Round 6
// 211.142 us; speedup vs baseline: 2.6186x; 2.6186x over previous
//
#include <hip/hip_runtime.h>

#define HEADS 4
#define OUTF 64
#define INF 64
#define NB 16  // nodes per proj block

// --- detect whether edge_index arrived as int64 (odd dwords all zero) or int32 ---
__global__ __launch_bounds__(64) void detect_i64(const int* __restrict__ ei, int* __restrict__ flag) {
    if (threadIdx.x == 0) {
        int all0 = 1;
        #pragma unroll
        for (int i = 1; i < 64; i += 2) all0 &= (ei[i] == 0);
        *flag = all0;  // 1 -> int64 layout, 0 -> int32 layout
    }
}

// --- fused: dst-degree histogram + h = x@W (bf16 out) + s_src/s_dst reductions ---
// block = 256 threads = 4 waves; wave w handles head w; lane = output feature o.
// W column held in VGPRs; the asm pin INSIDE the node loop forces residency
// (r3/r4 lesson: a pin before the loop lets the allocator spill the array back).
__global__ __launch_bounds__(256, 2) void proj_kernel(
    const float* __restrict__ x, const float* __restrict__ W,
    const float* __restrict__ a_src, const float* __restrict__ a_dst,
    ushort* __restrict__ h_bf, float* __restrict__ ssrc, float* __restrict__ sdst,
    const int* __restrict__ ei, const int* __restrict__ flag,
    int* __restrict__ cnt, int nNodes, int E)
{
    const int tid  = threadIdx.x;
    const int head = tid >> 6;
    const int o    = tid & 63;

    // fused histogram: this block's slice of edges
    const int estride = gridDim.x * 256;
    const int i64 = *flag;
    for (int i = blockIdx.x * 256 + tid; i < E; i += estride) {
        const int dst = i64 ? ei[2 * ((size_t)E + i)] : ei[(size_t)E + i];
        atomicAdd(&cnt[dst], 1);
    }

    float w[64];
    const float* Wp = W + (size_t)head * (INF * OUTF) + o;
    #pragma unroll
    for (int f = 0; f < 64; ++f) w[f] = Wp[f * OUTF];  // coalesced: 64 lanes x 4B per f

    const float asrc = a_src[tid];
    const float adst = a_dst[tid];

    const int n0 = blockIdx.x * NB;
    const int n1 = (n0 + NB < nNodes) ? (n0 + NB) : nNodes;
    int n = n0;
    for (; n + 1 < n1; n += 2) {
        // zero-instruction pin: each iteration requires all 64 w values in VGPRs,
        // so the allocator cannot sink the W loads or spill w to scratch.
        #pragma unroll
        for (int f = 0; f < 64; ++f) asm volatile("" : "+v"(w[f]));

        const float* xa = x + (size_t)n * INF;        // wave-uniform -> scalar loads
        const float* xb = xa + INF;
        float a0 = 0.f, a1 = 0.f, a2 = 0.f, a3 = 0.f;
        float b0 = 0.f, b1 = 0.f, b2 = 0.f, b3 = 0.f;
        #pragma unroll
        for (int f = 0; f < 64; f += 4) {             // 8 independent 16-deep chains
            a0 = fmaf(xa[f + 0], w[f + 0], a0);
            a1 = fmaf(xa[f + 1], w[f + 1], a1);
            a2 = fmaf(xa[f + 2], w[f + 2], a2);
            a3 = fmaf(xa[f + 3], w[f + 3], a3);
            b0 = fmaf(xb[f + 0], w[f + 0], b0);
            b1 = fmaf(xb[f + 1], w[f + 1], b1);
            b2 = fmaf(xb[f + 2], w[f + 2], b2);
            b3 = fmaf(xb[f + 3], w[f + 3], b3);
        }
        const float accA = (a0 + a1) + (a2 + a3);
        const float accB = (b0 + b1) + (b2 + b3);

        const unsigned ua = __float_as_uint(accA);
        const unsigned ub = __float_as_uint(accB);
        h_bf[(size_t)n * 256 + tid]       = (ushort)((ua + 0x7fffu + ((ua >> 16) & 1u)) >> 16);
        h_bf[(size_t)(n + 1) * 256 + tid] = (ushort)((ub + 0x7fffu + ((ub >> 16) & 1u)) >> 16);

        float rsA = accA * asrc, rdA = accA * adst;
        float rsB = accB * asrc, rdB = accB * adst;
        #pragma unroll
        for (int off = 32; off > 0; off >>= 1) {      // 4 interleaved reduce chains
            rsA += __shfl_xor(rsA, off);
            rdA += __shfl_xor(rdA, off);
            rsB += __shfl_xor(rsB, off);
            rdB += __shfl_xor(rdB, off);
        }
        if (o == 0) {
            ssrc[n * 4 + head] = rsA;  sdst[n * 4 + head] = rdA;
            ssrc[(n + 1) * 4 + head] = rsB;  sdst[(n + 1) * 4 + head] = rdB;
        }
    }
    for (; n < n1; ++n) {  // odd tail
        #pragma unroll
        for (int f = 0; f < 64; ++f) asm volatile("" : "+v"(w[f]));
        const float* xr = x + (size_t)n * INF;
        float a0 = 0.f, a1 = 0.f, a2 = 0.f, a3 = 0.f;
        #pragma unroll
        for (int f = 0; f < 64; f += 4) {
            a0 = fmaf(xr[f + 0], w[f + 0], a0);
            a1 = fmaf(xr[f + 1], w[f + 1], a1);
            a2 = fmaf(xr[f + 2], w[f + 2], a2);
            a3 = fmaf(xr[f + 3], w[f + 3], a3);
        }
        const float acc = (a0 + a1) + (a2 + a3);
        const unsigned u = __float_as_uint(acc);
        h_bf[(size_t)n * 256 + tid] = (ushort)((u + 0x7fffu + ((u >> 16) & 1u)) >> 16);
        float rs = acc * asrc, rd = acc * adst;
        #pragma unroll
        for (int off = 32; off > 0; off >>= 1) {
            rs += __shfl_xor(rs, off);
            rd += __shfl_xor(rd, off);
        }
        if (o == 0) { ssrc[n * 4 + head] = rs; sdst[n * 4 + head] = rd; }
    }
}

// --- parallel scan, stage 1: per-block (2048 elems) partial sums ---
__global__ __launch_bounds__(256) void scan_partial(
    const int* __restrict__ cnt, int* __restrict__ bsum, int N)
{
    const int t = threadIdx.x, lane = t & 63, wv = t >> 6;
    const int i0 = blockIdx.x * 2048 + t * 8;
    int s = 0;
    #pragma unroll
    for (int k = 0; k < 8; ++k) if (i0 + k < N) s += cnt[i0 + k];
    #pragma unroll
    for (int off = 32; off > 0; off >>= 1) s += __shfl_xor(s, off);
    __shared__ int ws[4];
    if (lane == 0) ws[wv] = s;
    __syncthreads();
    if (t == 0) bsum[blockIdx.x] = ws[0] + ws[1] + ws[2] + ws[3];
}

// --- stage 2: exclusive scan of block sums (nb <= 64, trivial serial) ---
__global__ __launch_bounds__(64) void scan_bsum(int* __restrict__ bsum, int nb)
{
    if (threadIdx.x == 0) {
        int run = 0;
        for (int b = 0; b < nb; ++b) { int v = bsum[b]; bsum[b] = run; run += v; }
    }
}

// --- stage 3: per-block re-scan with offset -> row_start[0..N], cursor[0..N) ---
__global__ __launch_bounds__(256) void scan_final(
    const int* __restrict__ cnt, const int* __restrict__ bsum,
    int* __restrict__ row_start, int* __restrict__ cursor, int N)
{
    const int t = threadIdx.x, lane = t & 63, wv = t >> 6;
    const int i0 = blockIdx.x * 2048 + t * 8;
    int v[8], s = 0;
    #pragma unroll
    for (int k = 0; k < 8; ++k) { v[k] = (i0 + k < N) ? cnt[i0 + k] : 0; s += v[k]; }
    int incl = s;
    #pragma unroll
    for (int d = 1; d < 64; d <<= 1) {
        int tm = __shfl_up(incl, d);
        if (lane >= d) incl += tm;
    }
    __shared__ int ws[4];
    if (lane == 63) ws[wv] = incl;
    __syncthreads();
    int woff = 0;
    for (int k = 0; k < wv; ++k) woff += ws[k];
    int run = bsum[blockIdx.x] + woff + incl - s;  // exclusive prefix at i0
    #pragma unroll
    for (int k = 0; k < 8; ++k) {
        if (i0 + k < N) { cursor[i0 + k] = run; row_start[i0 + k + 1] = run + v[k]; }
        run += v[k];
    }
    if (blockIdx.x == 0 && t == 0) row_start[0] = 0;
}

// --- place each edge's src into its dst's CSR slot ---
__global__ __launch_bounds__(256) void fill_kernel(
    const int* __restrict__ ei, const int* __restrict__ flag,
    int* __restrict__ cursor, int* __restrict__ csr_src, int E)
{
    const int i = blockIdx.x * 256 + threadIdx.x;
    if (i >= E) return;
    int src, dst;
    if (*flag) { src = ei[2 * (size_t)i]; dst = ei[2 * ((size_t)E + i)]; }
    else       { src = ei[i];             dst = ei[(size_t)E + i]; }
    const int pos = atomicAdd(&cursor[dst], 1);
    csr_src[pos] = src;
}

// --- one WAVE per dst node; lane covers 4 output features (uint2 bf16x4 loads) ---
__global__ __launch_bounds__(256) void gather_kernel(
    const int* __restrict__ row_start, const int* __restrict__ csr_src,
    const ushort* __restrict__ h_bf, const float* __restrict__ ssrc,
    const float* __restrict__ sdst, float* __restrict__ out, int N)
{
    const int tid  = threadIdx.x;
    const int lane = tid & 63;
    const int n    = blockIdx.x * 4 + (tid >> 6);
    if (n >= N) return;
    const int head = lane >> 4;  // features lane*4..lane*4+3 all in this head
    const int start = row_start[n];
    const int end   = row_start[n + 1];
    const float sd  = sdst[n * 4 + head];

    float a0 = 0.f, a1 = 0.f, a2 = 0.f, a3 = 0.f, wsum = 0.f;
    int c = start;
    for (; c + 64 <= end; c += 64) {
        const int sv = csr_src[c + lane];
        #pragma unroll 4
        for (int j = 0; j < 64; ++j) {
            const int s = __shfl(sv, j);
            float e = ssrc[s * 4 + head] + sd;
            e = e >= 0.f ? e : 0.2f * e;
            const float w = __expf(e);
            const uint2 hv = *reinterpret_cast<const uint2*>(h_bf + ((size_t)s << 8) + (lane << 2));
            a0 = fmaf(w, __uint_as_float(hv.x << 16), a0);
            a1 = fmaf(w, __uint_as_float(hv.x & 0xffff0000u), a1);
            a2 = fmaf(w, __uint_as_float(hv.y << 16), a2);
            a3 = fmaf(w, __uint_as_float(hv.y & 0xffff0000u), a3);
            wsum += w;
        }
    }
    const int rem = end - c;
    if (rem > 0) {
        const int sv = (lane < rem) ? csr_src[c + lane] : 0;
        for (int j = 0; j < rem; ++j) {
            const int s = __shfl(sv, j);
            float e = ssrc[s * 4 + head] + sd;
            e = e >= 0.f ? e : 0.2f * e;
            const float w = __expf(e);
            const uint2 hv = *reinterpret_cast<const uint2*>(h_bf + ((size_t)s << 8) + (lane << 2));
            a0 = fmaf(w, __uint_as_float(hv.x << 16), a0);
            a1 = fmaf(w, __uint_as_float(hv.x & 0xffff0000u), a1);
            a2 = fmaf(w, __uint_as_float(hv.y << 16), a2);
            a3 = fmaf(w, __uint_as_float(hv.y & 0xffff0000u), a3);
            wsum += w;
        }
    }
    const float inv = 1.f / (wsum + 1e-16f);
    float4 o;
    o.x = a0 * inv; o.y = a1 * inv; o.z = a2 * inv; o.w = a3 * inv;
    *reinterpret_cast<float4*>(out + ((size_t)n << 8) + (lane << 2)) = o;
}

extern "C" void kernel_launch(void* const* d_in, const int* in_sizes, int n_in,
                              void* d_out, int out_size, void* d_ws, size_t ws_size,
                              hipStream_t stream) {
    const float* x     = (const float*)d_in[0];
    const int*   ei    = (const int*)d_in[1];
    const float* W     = (const float*)d_in[2];
    const float* a_src = (const float*)d_in[3];
    const float* a_dst = (const float*)d_in[4];
    float*       out   = (float*)d_out;

    const int N = in_sizes[0] / INF;   // 50000
    const int E = in_sizes[1] / 2;     // 800000

    // workspace: h_bf[N*256 ushort] | ssrc[N*4] | sdst[N*4] | cnt[N] | row_start[N+1] | cursor[N] | csr_src[E] | bsum[64] | flag
    ushort* h_bf     = (ushort*)d_ws;
    float* ssrc      = (float*)(h_bf + (size_t)N * 256);
    float* sdst      = ssrc + (size_t)N * 4;
    int*   cnt       = (int*)(sdst + (size_t)N * 4);
    int*   row_start = cnt + N;
    int*   cursor    = row_start + (N + 1);
    int*   csr_src   = cursor + N;
    int*   bsum      = csr_src + E;
    int*   flag      = bsum + 64;

    const int nb = (N + 2047) / 2048;

    hipMemsetAsync(cnt, 0, (size_t)N * sizeof(int), stream);

    detect_i64<<<1, 64, 0, stream>>>(ei, flag);
    proj_kernel<<<(N + NB - 1) / NB, 256, 0, stream>>>(x, W, a_src, a_dst, h_bf, ssrc, sdst, ei, flag, cnt, N, E);
    scan_partial<<<nb, 256, 0, stream>>>(cnt, bsum, N);
    scan_bsum<<<1, 64, 0, stream>>>(bsum, nb);
    scan_final<<<nb, 256, 0, stream>>>(cnt, bsum, row_start, cursor, N);
    fill_kernel<<<(E + 255) / 256, 256, 0, stream>>>(ei, flag, cursor, csr_src, E);
    gather_kernel<<<(N + 3) / 4, 256, 0, stream>>>(row_start, csr_src, h_bf, ssrc, sdst, out, N);
}